// Round 3
// baseline (83.764 us; speedup 1.0000x reference)
//
#include <hip/hip_runtime.h>

// Adaptive avg pool 8x224x224x256 NHWC fp32 -> 8x7x7x256.
// 224/7 = 32 exactly => uniform 32x32 windows.
// Row-streaming two-phase:
//   Phase 1: one block per (b,row) — 1792 blocks = exactly 7/CU. Each block
//            streams its whole 224KB row contiguously and emits per-(ow,c)
//            column sums (7*256 floats) to ws.
//   Phase 2: sum 32 row-partials per output site, scale, write d_out.

constexpr int B  = 8;
constexpr int H  = 224;
constexpr int W  = 224;
constexpr int C  = 256;
constexpr int OH = 7;
constexpr int OW = 7;
constexpr int WIN = 32;
constexpr int G  = C / 4;                      // 64 float4 channel groups
constexpr int F4_PER_ROW = W * G;              // 14336 float4 per row
constexpr int ITERS = F4_PER_ROW / 256;        // 56 loads/thread
constexpr int OUT_ELEMS = B * OH * OW * C;     // 100352
constexpr int NROWS = B * H;                   // 1792
constexpr size_t WS_ROW_NEEDED = (size_t)NROWS * OW * C * sizeof(float);  // 12.25 MB

__global__ __launch_bounds__(256) void row_stream_kernel(const float* __restrict__ x,
                                                         float* __restrict__ ws) {
    const int rowid = blockIdx.x;              // (b*H + row)
    const int tid   = threadIdx.x;
    const int c4    = tid & (G - 1);           // float4 channel group
    const int col0  = tid >> 6;                // 0..3 column phase

    const float4* p = reinterpret_cast<const float4*>(x) + (size_t)rowid * F4_PER_ROW + tid;

    float4 acc[OW];
#pragma unroll
    for (int o = 0; o < OW; ++o) acc[o] = make_float4(0.f, 0.f, 0.f, 0.f);

    // thread's m-th load covers col = col0 + 4m, ow = m>>3 (exact since 32/4=8)
#pragma unroll
    for (int m = 0; m < ITERS; ++m) {
        float4 v = p[(size_t)m * 256];
        const int o = m >> 3;
        acc[o].x += v.x; acc[o].y += v.y; acc[o].z += v.z; acc[o].w += v.w;
    }

    // reduce across the 4 column phases (threads tid, tid+64, tid+128, tid+192)
    __shared__ float4 lds[OW][2][G];           // 14336 B

    if (col0 >= 2) {
#pragma unroll
        for (int o = 0; o < OW; ++o) lds[o][col0 - 2][c4] = acc[o];
    }
    __syncthreads();
    if (col0 < 2) {
#pragma unroll
        for (int o = 0; o < OW; ++o) {
            float4 v = lds[o][col0][c4];
            acc[o].x += v.x; acc[o].y += v.y; acc[o].z += v.z; acc[o].w += v.w;
        }
    }
    __syncthreads();
    if (col0 == 1) {
#pragma unroll
        for (int o = 0; o < OW; ++o) lds[o][0][c4] = acc[o];
    }
    __syncthreads();
    if (col0 == 0) {
        float4* wrow = reinterpret_cast<float4*>(ws) + (size_t)rowid * (OW * G);
#pragma unroll
        for (int o = 0; o < OW; ++o) {
            float4 v = lds[o][0][c4];
            v.x += acc[o].x; v.y += acc[o].y; v.z += acc[o].z; v.w += acc[o].w;
            wrow[o * G + c4] = v;
        }
    }
}

__global__ __launch_bounds__(256) void row_reduce_kernel(const float* __restrict__ ws,
                                                         float* __restrict__ out) {
    int i = blockIdx.x * 256 + threadIdx.x;    // output element id
    if (i >= OUT_ELEMS) return;
    int c  = i & (C - 1);
    int t  = i >> 8;
    int ow = t % OW; t /= OW;
    int oh = t % OH; t /= OH;
    int b  = t;

    const float* p = ws + (((size_t)(b * H + oh * WIN) * OW) + ow) * C + c;
    float s = 0.f;
#pragma unroll
    for (int r = 0; r < WIN; ++r) s += p[(size_t)r * OW * C];
    out[i] = s * (1.0f / (float)(WIN * WIN));
}

// ---------------- fallback: chunked two-phase (R2 kernel) ----------------
constexpr int CHUNKS = 8;
constexpr int ROWS_PER_CHUNK = WIN / CHUNKS;
constexpr int NCHUNK_BLOCKS = B * OH * OW * CHUNKS;
constexpr size_t WS_CHUNK_NEEDED = (size_t)NCHUNK_BLOCKS * C * sizeof(float);

__global__ __launch_bounds__(256) void pool_partial_kernel(const float* __restrict__ x,
                                                           float* __restrict__ ws) {
    int bid   = blockIdx.x;
    int chunk = bid & (CHUNKS - 1);
    int t     = bid >> 3;
    int ow    = t % OW; t /= OW;
    int oh    = t % OH; t /= OH;
    int b     = t;

    int tid = threadIdx.x;
    int g   = tid & (G - 1);
    int r   = tid >> 6;

    int row  = oh * WIN + chunk * ROWS_PER_CHUNK + r;
    int col0 = ow * WIN;

    const float4* p = reinterpret_cast<const float4*>(
        x + (((size_t)b * H + row) * W + col0) * C) + g;

    float4 acc = make_float4(0.f, 0.f, 0.f, 0.f);
#pragma unroll
    for (int c = 0; c < WIN; ++c) {
        float4 v = p[(size_t)c * G];
        acc.x += v.x; acc.y += v.y; acc.z += v.z; acc.w += v.w;
    }

    __shared__ float4 lds[ROWS_PER_CHUNK][G];
    lds[r][g] = acc;
    __syncthreads();

    if (r == 0) {
        float4 a0 = lds[0][g];
        float4 a1 = lds[1][g];
        float4 a2 = lds[2][g];
        float4 a3 = lds[3][g];
        float4 s;
        s.x = a0.x + a1.x + a2.x + a3.x;
        s.y = a0.y + a1.y + a2.y + a3.y;
        s.z = a0.z + a1.z + a2.z + a3.z;
        s.w = a0.w + a1.w + a2.w + a3.w;
        reinterpret_cast<float4*>(ws)[(size_t)bid * G + g] = s;
    }
}

__global__ __launch_bounds__(256) void reduce_kernel(const float* __restrict__ ws,
                                                     float* __restrict__ out) {
    int i = blockIdx.x * 256 + threadIdx.x;
    if (i >= OUT_ELEMS) return;
    int o = i >> 8;
    int c = i & (C - 1);
    const float* p = ws + (size_t)(o * CHUNKS) * C + c;
    float s = 0.f;
#pragma unroll
    for (int k = 0; k < CHUNKS; ++k) s += p[(size_t)k * C];
    out[i] = s * (1.0f / (float)(WIN * WIN));
}

extern "C" void kernel_launch(void* const* d_in, const int* in_sizes, int n_in,
                              void* d_out, int out_size, void* d_ws, size_t ws_size,
                              hipStream_t stream) {
    const float* x = (const float*)d_in[0];
    float* out = (float*)d_out;
    float* ws = (float*)d_ws;

    if (ws_size >= WS_ROW_NEEDED) {
        row_stream_kernel<<<NROWS, 256, 0, stream>>>(x, ws);
        row_reduce_kernel<<<(OUT_ELEMS + 255) / 256, 256, 0, stream>>>(ws, out);
    } else {
        pool_partial_kernel<<<NCHUNK_BLOCKS, 256, 0, stream>>>(x, ws);
        reduce_kernel<<<(OUT_ELEMS + 255) / 256, 256, 0, stream>>>(ws, out);
    }
}

// Round 4
// 69.212 us; speedup vs baseline: 1.2103x; 1.2103x over previous
//
#include <hip/hip_runtime.h>

// Adaptive avg pool 8x224x224x256 NHWC fp32 -> 8x7x7x256.
// 224/7 = 32 exactly => uniform 32x32 windows, each output = mean of 1024 pixels.
// R2 two-phase structure (best so far: 78.2us), plus:
//   - explicit 8-deep load batching (force outstanding-load depth)
//   - nontemporal input loads (read-once stream, bypass L2 allocate)
//   - __launch_bounds__(256,8) -> 32 waves/CU

typedef float f32x4 __attribute__((ext_vector_type(4)));

constexpr int B  = 8;
constexpr int H  = 224;
constexpr int W  = 224;
constexpr int C  = 256;
constexpr int OH = 7;
constexpr int OW = 7;
constexpr int WIN = 32;          // window size in both dims
constexpr int CHUNKS = 8;        // row-chunks per window
constexpr int ROWS_PER_CHUNK = WIN / CHUNKS;   // 4
constexpr int G  = C / 4;        // 64 float4 channel groups
constexpr int OUT_ELEMS = B * OH * OW * C;     // 100352
constexpr int NCHUNK_BLOCKS = B * OH * OW * CHUNKS;  // 3136
constexpr size_t WS_NEEDED = (size_t)NCHUNK_BLOCKS * C * sizeof(float);  // 3.2 MB
constexpr int BATCH = 8;
constexpr int NBATCH = WIN / BATCH;            // 4

__global__ __launch_bounds__(256, 8) void pool_partial_kernel(const float* __restrict__ x,
                                                              float* __restrict__ ws) {
    int bid   = blockIdx.x;
    int chunk = bid & (CHUNKS - 1);
    int t     = bid >> 3;
    int ow    = t % OW; t /= OW;
    int oh    = t % OH; t /= OH;
    int b     = t;

    int tid = threadIdx.x;
    int g   = tid & (G - 1);      // float4 channel group, 0..63
    int r   = tid >> 6;           // row within chunk, 0..3

    int row  = oh * WIN + chunk * ROWS_PER_CHUNK + r;
    int col0 = ow * WIN;

    const f32x4* p = reinterpret_cast<const f32x4*>(
        x + (((size_t)b * H + row) * W + col0) * C) + g;

    f32x4 acc = (f32x4)0.0f;
#pragma unroll
    for (int bt = 0; bt < NBATCH; ++bt) {
        f32x4 v[BATCH];
#pragma unroll
        for (int j = 0; j < BATCH; ++j)
            v[j] = __builtin_nontemporal_load(&p[(size_t)(bt * BATCH + j) * G]);
#pragma unroll
        for (int j = 0; j < BATCH; ++j)
            acc += v[j];
    }

    __shared__ f32x4 lds[ROWS_PER_CHUNK][G];
    lds[r][g] = acc;
    __syncthreads();

    if (r == 0) {
        f32x4 s = lds[0][g] + lds[1][g] + lds[2][g] + lds[3][g];
        reinterpret_cast<f32x4*>(ws)[(size_t)bid * G + g] = s;  // contiguous 1 KiB/block
    }
}

__global__ __launch_bounds__(256) void reduce_kernel(const float* __restrict__ ws,
                                                     float* __restrict__ out) {
    int i = blockIdx.x * 256 + threadIdx.x;   // output element id
    if (i >= OUT_ELEMS) return;
    int o = i >> 8;           // output site (b,oh,ow), matches pool's bid>>3 order
    int c = i & (C - 1);
    const float* p = ws + (size_t)(o * CHUNKS) * C + c;
    float s = 0.f;
#pragma unroll
    for (int k = 0; k < CHUNKS; ++k) s += p[(size_t)k * C];
    out[i] = s * (1.0f / (float)(WIN * WIN));
}

// ---- fallback (atomic) path, used only if ws_size is unexpectedly small ----
__global__ void zero_out_kernel(float* __restrict__ out, int n) {
    int i = blockIdx.x * blockDim.x + threadIdx.x;
    if (i < n) out[i] = 0.0f;
}

__global__ __launch_bounds__(256) void pool_atomic_kernel(const float* __restrict__ x,
                                                          float* __restrict__ out) {
    int bid   = blockIdx.x;
    int chunk = bid & (CHUNKS - 1);
    int t     = bid >> 3;
    int ow    = t % OW; t /= OW;
    int oh    = t % OH; t /= OH;
    int b     = t;

    int tid = threadIdx.x;
    int g   = tid & (G - 1);
    int r   = tid >> 6;

    int row  = oh * WIN + chunk * ROWS_PER_CHUNK + r;
    int col0 = ow * WIN;

    const f32x4* p = reinterpret_cast<const f32x4*>(
        x + (((size_t)b * H + row) * W + col0) * C) + g;

    f32x4 acc = (f32x4)0.0f;
#pragma unroll
    for (int c = 0; c < WIN; ++c)
        acc += p[(size_t)c * G];

    __shared__ f32x4 lds[ROWS_PER_CHUNK][G];
    lds[r][g] = acc;
    __syncthreads();

    if (r == 0) {
        f32x4 s = lds[0][g] + lds[1][g] + lds[2][g] + lds[3][g];
        const float k = 1.0f / (float)(WIN * WIN);
        float* o = out + (size_t)(bid >> 3) * C + g * 4;
        atomicAdd(o + 0, s.x * k);
        atomicAdd(o + 1, s.y * k);
        atomicAdd(o + 2, s.z * k);
        atomicAdd(o + 3, s.w * k);
    }
}

extern "C" void kernel_launch(void* const* d_in, const int* in_sizes, int n_in,
                              void* d_out, int out_size, void* d_ws, size_t ws_size,
                              hipStream_t stream) {
    const float* x = (const float*)d_in[0];
    float* out = (float*)d_out;

    if (ws_size >= WS_NEEDED) {
        float* ws = (float*)d_ws;
        pool_partial_kernel<<<NCHUNK_BLOCKS, 256, 0, stream>>>(x, ws);
        reduce_kernel<<<(OUT_ELEMS + 255) / 256, 256, 0, stream>>>(ws, out);
    } else {
        zero_out_kernel<<<(OUT_ELEMS + 255) / 256, 256, 0, stream>>>(out, OUT_ELEMS);
        pool_atomic_kernel<<<NCHUNK_BLOCKS, 256, 0, stream>>>(x, out);
    }
}